// Round 2
// baseline (3046.487 us; speedup 1.0000x reference)
//
#include <hip/hip_runtime.h>
#include <math.h>

#define N_NODES    100000
#define N_EDGES    3200000
#define N_GRAPHS   128
#define IN_DIM     128
#define HID        64
#define OUT_DIM    128
#define NBKT       391          // ceil(N_NODES / 256)
#define BIN_BLOCKS 512
#define E_PER_BIN  6250         // N_EDGES / BIN_BLOCKS (exact)

// ---------------- degree count ----------------
__global__ void k_count(const int* __restrict__ dst, int* __restrict__ cnt) {
    int i = blockIdx.x * 256 + threadIdx.x;
    if (i < N_EDGES) atomicAdd(&cnt[dst[i]], 1);
}

// ---------------- dinv = 1/sqrt(deg+1) ----------------
__global__ void k_dinv(const int* __restrict__ cnt, float* __restrict__ dinv) {
    int i = blockIdx.x * 256 + threadIdx.x;
    if (i < N_NODES) dinv[i] = 1.0f / sqrtf((float)cnt[i] + 1.0f);
}

// ---------------- per-bucket edge counts (bucket = dst >> 8) ----------------
__global__ void k_bucket_cnt(const int* __restrict__ cnt, int* __restrict__ bkt_cnt) {
    int b = blockIdx.x, t = threadIdx.x;
    int n = b * 256 + t;
    int v = (n < N_NODES) ? cnt[n] : 0;
#pragma unroll
    for (int off = 32; off > 0; off >>= 1) v += __shfl_down(v, off, 64);
    __shared__ int ws[4];
    int lane = t & 63, w = t >> 6;
    if (lane == 0) ws[w] = v;
    __syncthreads();
    if (t == 0) bkt_cnt[b] = ws[0] + ws[1] + ws[2] + ws[3];
}

// ---------------- exclusive scan over NBKT bucket counts (single block) ----
__global__ void k_scan_bkt(int* __restrict__ bc, int* __restrict__ cursor, int nb) {
    __shared__ int s[512];
    int t = threadIdx.x;
    int v = (t < nb) ? bc[t] : 0;
    s[t] = v; __syncthreads();
    for (int d = 1; d < 512; d <<= 1) {
        int add = (t >= d) ? s[t - d] : 0;
        __syncthreads();
        s[t] += add;
        __syncthreads();
    }
    int excl = s[t] - v;                    // exclusive prefix
    if (t <= nb) bc[t] = excl;              // bc[nb] = total = N_EDGES
    if (t < nb) cursor[t] = excl;
}

// ---------------- multisplit binning: recs[pos] = (src<<8)|dst_local --------
__global__ __launch_bounds__(256) void k_bin(const int* __restrict__ src,
                                             const int* __restrict__ dst,
                                             int* __restrict__ bkt_cursor,
                                             unsigned int* __restrict__ recs) {
    __shared__ int hist[NBKT];
    __shared__ int base[NBKT];
    int t = threadIdx.x;
    int e0 = blockIdx.x * E_PER_BIN;
    int e1 = e0 + E_PER_BIN;                 // exact fit: 512*6250 = 3.2M
    for (int b = t; b < NBKT; b += 256) hist[b] = 0;
    __syncthreads();
    // phase A: local histogram
    for (int e = e0 + t; e < e1; e += 256)
        atomicAdd(&hist[dst[e] >> 8], 1);
    __syncthreads();
    // phase B: reserve chunks in global bucket regions
    for (int b = t; b < NBKT; b += 256) {
        int h = hist[b];
        base[b] = h ? atomicAdd(&bkt_cursor[b], h) : 0;
        hist[b] = 0;
    }
    __syncthreads();
    // phase C: place records
    for (int e = e0 + t; e < e1; e += 256) {
        int d = dst[e];
        int b = d >> 8;
        int pos = base[b] + atomicAdd(&hist[b], 1);
        recs[pos] = ((unsigned int)src[e] << 8) | (unsigned int)(d & 255);
    }
}

// ---------------- dense GEMM  Y[N,64] = dinv[n] * (X[N,K] @ W[K,64]) --------
template <int K>
__global__ __launch_bounds__(256) void k_gemm(const float* __restrict__ X,
                                              const float* __restrict__ W,
                                              const float* __restrict__ dinv,
                                              float* __restrict__ Y, int nrows) {
    __shared__ float Ws[K * 64];
    __shared__ float Xs[16][K];
    int t = threadIdx.x;
    for (int i = t; i < K * 64; i += 256) Ws[i] = W[i];
    int row0 = blockIdx.x * 16;
    for (int i = t; i < 16 * K; i += 256) {
        int r = i / K, k = i % K;
        int gr = row0 + r;
        Xs[r][k] = (gr < nrows) ? X[gr * K + k] : 0.0f;
    }
    __syncthreads();
    int c = t & 63, rg = t >> 6;
    float acc[4] = {0.f, 0.f, 0.f, 0.f};
#pragma unroll 4
    for (int k = 0; k < K; ++k) {
        float w = Ws[k * 64 + c];
#pragma unroll
        for (int i = 0; i < 4; ++i) acc[i] += Xs[rg * 4 + i][k] * w;
    }
#pragma unroll
    for (int i = 0; i < 4; ++i) {
        int gr = row0 + rg * 4 + i;
        if (gr < nrows) Y[gr * 64 + c] = dinv[gr] * acc[i];
    }
}

// ---------------- fused bucket aggregate + self-loop + bias + relu ----------
// one block per bucket; 256x64 fp32 accumulator in LDS; xwp is dinv-prescaled
__global__ __launch_bounds__(256) void k_agg(const float* __restrict__ xwp,
                                             const float* __restrict__ dinv,
                                             const int* __restrict__ bkt_ptr,
                                             const unsigned int* __restrict__ recs,
                                             const float* __restrict__ bias,
                                             float* __restrict__ hout) {
    __shared__ float acc[256 * 64];
    int t = threadIdx.x;
    int lane = t & 63, w = t >> 6;
    for (int k = t; k < 256 * 64; k += 256) acc[k] = 0.0f;
    __syncthreads();
    int b = blockIdx.x;
    int start = bkt_ptr[b], end = bkt_ptr[b + 1];
    int i = start + w;
    // 4-deep software pipeline per wave (stride 16 across the 4 waves)
    for (; i + 12 < end; i += 16) {
        unsigned int r0 = recs[i], r1 = recs[i + 4], r2 = recs[i + 8], r3 = recs[i + 12];
        float v0 = xwp[(r0 >> 8) * 64 + lane];
        float v1 = xwp[(r1 >> 8) * 64 + lane];
        float v2 = xwp[(r2 >> 8) * 64 + lane];
        float v3 = xwp[(r3 >> 8) * 64 + lane];
        atomicAdd(&acc[(r0 & 255u) * 64 + lane], v0);
        atomicAdd(&acc[(r1 & 255u) * 64 + lane], v1);
        atomicAdd(&acc[(r2 & 255u) * 64 + lane], v2);
        atomicAdd(&acc[(r3 & 255u) * 64 + lane], v3);
    }
    for (; i < end; i += 4) {
        unsigned int r = recs[i];
        float v = xwp[(r >> 8) * 64 + lane];
        atomicAdd(&acc[(r & 255u) * 64 + lane], v);
    }
    __syncthreads();
    // epilogue: h[n] = relu(dinv[n] * (acc + xwp[n]) + bias)
    int n0 = b * 256;
    for (int dl = w; dl < 256; dl += 4) {
        int n = n0 + dl;
        if (n >= N_NODES) break;
        float v = acc[dl * 64 + lane] + xwp[n * 64 + lane];
        hout[n * 64 + lane] = fmaxf(dinv[n] * v + bias[lane], 0.0f);
    }
}

// ---------------- mean pool (batch is sorted) ----------------
__device__ __forceinline__ int lower_bound(const int* __restrict__ a, int n, int key) {
    int lo = 0, hi = n;
    while (lo < hi) {
        int mid = (lo + hi) >> 1;
        if (a[mid] < key) lo = mid + 1; else hi = mid;
    }
    return lo;
}

__global__ void k_pool(const float* __restrict__ h, const int* __restrict__ batch,
                       float* __restrict__ g) {
    int b = blockIdx.x;
    int t = threadIdx.x, c = t & 63, rg = t >> 6;
    __shared__ float s[4][64];
    int start = lower_bound(batch, N_NODES, b);
    int end   = lower_bound(batch, N_NODES, b + 1);
    float sum = 0.f;
    for (int n = start + rg; n < end; n += 4) sum += h[(size_t)n * 64 + c];
    s[rg][c] = sum;
    __syncthreads();
    if (rg == 0) {
        float tot = s[0][c] + s[1][c] + s[2][c] + s[3][c];
        float cntf = (float)(end - start);
        g[b * 64 + c] = tot / fmaxf(cntf, 1.0f);
    }
}

// ---------------- final linear  out[128,128] = g[128,64] @ Wl[64,128] + bl --
__global__ void k_final(const float* __restrict__ g, const float* __restrict__ Wl,
                        const float* __restrict__ bl, float* __restrict__ out) {
    __shared__ float gs[64];
    int row = blockIdx.x, c = threadIdx.x;
    if (c < 64) gs[c] = g[row * 64 + c];
    __syncthreads();
    float acc = bl[c];
#pragma unroll
    for (int k = 0; k < 64; ++k) acc += gs[k] * Wl[k * 128 + c];
    out[row * 128 + c] = acc;
}

extern "C" void kernel_launch(void* const* d_in, const int* in_sizes, int n_in,
                              void* d_out, int out_size, void* d_ws, size_t ws_size,
                              hipStream_t stream) {
    const float* x    = (const float*)d_in[0];
    const int*   ei   = (const int*)d_in[1];
    const int*   batch= (const int*)d_in[2];
    const float* W1   = (const float*)d_in[3];
    const float* b1   = (const float*)d_in[4];
    const float* W2   = (const float*)d_in[5];
    const float* b2   = (const float*)d_in[6];
    const float* Wl   = (const float*)d_in[7];
    const float* bl   = (const float*)d_in[8];
    float* out = (float*)d_out;

    const int* src = ei;
    const int* dst = ei + N_EDGES;

    // workspace layout (offsets 256B aligned)
    char* base = (char*)d_ws;
    int*          cnt      = (int*)         (base + 0);           // 400000
    float*        dinv     = (float*)       (base + 400128);      // 400000
    int*          bkt_ptr  = (int*)         (base + 800256);      // (NBKT+1)*4
    int*          bkt_cur  = (int*)         (base + 802304);      // NBKT*4
    unsigned int* recs     = (unsigned int*)(base + 804352);      // 12.8 MB
    float*        bufA     = (float*)       (base + 13604352);    // 25.6 MB
    float*        bufB     = (float*)       (base + 39204352);    // 25.6 MB
    float*        g        = (float*)       (base + 64804352);    // 32 KB

    const int GB_E = (N_EDGES + 255) / 256;     // 12500
    const int GB_N = (N_NODES + 255) / 256;     // 391

    hipMemsetAsync(cnt, 0, N_NODES * sizeof(int), stream);
    k_count     <<<GB_E, 256, 0, stream>>>(dst, cnt);
    k_dinv      <<<GB_N, 256, 0, stream>>>(cnt, dinv);
    k_bucket_cnt<<<NBKT, 256, 0, stream>>>(cnt, bkt_ptr);
    k_scan_bkt  <<<1, 512, 0, stream>>>(bkt_ptr, bkt_cur, NBKT);
    k_bin       <<<BIN_BLOCKS, 256, 0, stream>>>(src, dst, bkt_cur, recs);

    // layer 1: bufA = dinv .* (x @ W1); bufB = relu(dinv.*(agg + bufA) + b1)
    k_gemm<IN_DIM><<<(N_NODES + 15) / 16, 256, 0, stream>>>(x, W1, dinv, bufA, N_NODES);
    k_agg<<<NBKT, 256, 0, stream>>>(bufA, dinv, bkt_ptr, recs, b1, bufB);

    // layer 2
    k_gemm<HID><<<(N_NODES + 15) / 16, 256, 0, stream>>>(bufB, W2, dinv, bufA, N_NODES);
    k_agg<<<NBKT, 256, 0, stream>>>(bufA, dinv, bkt_ptr, recs, b2, bufB);

    // pool + final linear
    k_pool <<<N_GRAPHS, 256, 0, stream>>>(bufB, batch, g);
    k_final<<<N_GRAPHS, 128, 0, stream>>>(g, Wl, bl, out);
}

// Round 3
// 565.264 us; speedup vs baseline: 5.3895x; 5.3895x over previous
//
#include <hip/hip_runtime.h>
#include <math.h>

#define N_NODES    100000
#define N_EDGES    3200000
#define N_GRAPHS   128
#define IN_DIM     128
#define HID        64
#define OUT_DIM    128
#define NBKT       391          // ceil(N_NODES / 256)
#define BIN_BLOCKS 512
#define E_PER_BIN  6250         // N_EDGES / BIN_BLOCKS (exact)

// ---------------- degree count ----------------
__global__ void k_count(const int* __restrict__ dst, int* __restrict__ cnt) {
    int i = blockIdx.x * 256 + threadIdx.x;
    if (i < N_EDGES) atomicAdd(&cnt[dst[i]], 1);
}

// ---------------- dinv = 1/sqrt(deg+1) ----------------
__global__ void k_dinv(const int* __restrict__ cnt, float* __restrict__ dinv) {
    int i = blockIdx.x * 256 + threadIdx.x;
    if (i < N_NODES) dinv[i] = 1.0f / sqrtf((float)cnt[i] + 1.0f);
}

// ---------------- prefix sum over per-node counts (3 stages) ----------------
__global__ void k_scan1(const int* __restrict__ cnt, int* __restrict__ partial,
                        int* __restrict__ blockSums) {
    __shared__ int s[256];
    int t = threadIdx.x, i = blockIdx.x * 256 + t;
    int v = (i < N_NODES) ? cnt[i] : 0;
    s[t] = v; __syncthreads();
    for (int d = 1; d < 256; d <<= 1) {
        int add = (t >= d) ? s[t - d] : 0;
        __syncthreads();
        s[t] += add;
        __syncthreads();
    }
    if (i < N_NODES) partial[i] = s[t] - v;   // exclusive within block
    if (t == 255) blockSums[blockIdx.x] = s[t];
}

__global__ void k_scan2(int* __restrict__ blockSums, int nb) {
    __shared__ int s[512];
    int t = threadIdx.x;
    int v = (t < nb) ? blockSums[t] : 0;
    s[t] = v; __syncthreads();
    for (int d = 1; d < 512; d <<= 1) {
        int add = (t >= d) ? s[t - d] : 0;
        __syncthreads();
        s[t] += add;
        __syncthreads();
    }
    if (t < nb) blockSums[t] = s[t] - v;      // exclusive
}

__global__ void k_scan3(int* __restrict__ row_ptr, const int* __restrict__ blockSums,
                        int* __restrict__ bkt_cur) {
    int i = blockIdx.x * 256 + threadIdx.x;
    if (i < N_NODES) {
        int r = row_ptr[i] + blockSums[blockIdx.x];
        row_ptr[i] = r;
        if (threadIdx.x == 0) bkt_cur[blockIdx.x] = r;  // bucket start cursor
    }
    if (i == 0) row_ptr[N_NODES] = N_EDGES;
}

// ---------------- multisplit binning: recs[pos] = (src<<8)|dst_local --------
// each block's writes per bucket land in one contiguous reserved chunk
__global__ __launch_bounds__(256) void k_bin(const int* __restrict__ src,
                                             const int* __restrict__ dst,
                                             int* __restrict__ bkt_cursor,
                                             unsigned int* __restrict__ recs) {
    __shared__ int hist[NBKT];
    __shared__ int base[NBKT];
    int t = threadIdx.x;
    int e0 = blockIdx.x * E_PER_BIN;
    int e1 = e0 + E_PER_BIN;                 // exact: 512*6250 = 3.2M
    for (int b = t; b < NBKT; b += 256) hist[b] = 0;
    __syncthreads();
    for (int e = e0 + t; e < e1; e += 256)
        atomicAdd(&hist[dst[e] >> 8], 1);
    __syncthreads();
    for (int b = t; b < NBKT; b += 256) {
        int h = hist[b];
        base[b] = h ? atomicAdd(&bkt_cursor[b], h) : 0;
        hist[b] = 0;
    }
    __syncthreads();
    for (int e = e0 + t; e < e1; e += 256) {
        int d = dst[e];
        int b = d >> 8;
        int pos = base[b] + atomicAdd(&hist[b], 1);
        recs[pos] = ((unsigned int)src[e] << 8) | (unsigned int)(d & 255);
    }
}

// ---------------- per-bucket CSR finalize (writes stay in one 32KB region) --
__global__ __launch_bounds__(256) void k_csr(const unsigned int* __restrict__ recs,
                                             const int* __restrict__ row_ptr,
                                             int* __restrict__ csr_src) {
    __shared__ int lcur[256];
    int b = blockIdx.x, t = threadIdx.x;
    int n = b * 256 + t;
    lcur[t] = (n < N_NODES) ? row_ptr[n] : N_EDGES;
    int start = row_ptr[b * 256];
    int nend = (b + 1) * 256;
    int end = (nend <= N_NODES) ? row_ptr[nend] : N_EDGES;
    __syncthreads();
    for (int i = start + t; i < end; i += 256) {
        unsigned int r = recs[i];
        int p = atomicAdd(&lcur[r & 255u], 1);
        csr_src[p] = (int)(r >> 8);
    }
}

// ---------------- dense GEMM  Y[N,64] = dinv[n] * (X[N,K] @ W[K,64]) --------
template <int K>
__global__ __launch_bounds__(256) void k_gemm(const float* __restrict__ X,
                                              const float* __restrict__ W,
                                              const float* __restrict__ dinv,
                                              float* __restrict__ Y, int nrows) {
    __shared__ float Ws[K * 64];
    __shared__ float Xs[16][K];
    int t = threadIdx.x;
    for (int i = t; i < K * 64; i += 256) Ws[i] = W[i];
    int row0 = blockIdx.x * 16;
    for (int i = t; i < 16 * K; i += 256) {
        int r = i / K, k = i % K;
        int gr = row0 + r;
        Xs[r][k] = (gr < nrows) ? X[gr * K + k] : 0.0f;
    }
    __syncthreads();
    int c = t & 63, rg = t >> 6;
    float acc[4] = {0.f, 0.f, 0.f, 0.f};
#pragma unroll 4
    for (int k = 0; k < K; ++k) {
        float w = Ws[k * 64 + c];
#pragma unroll
        for (int i = 0; i < 4; ++i) acc[i] += Xs[rg * 4 + i][k] * w;
    }
#pragma unroll
    for (int i = 0; i < 4; ++i) {
        int gr = row0 + rg * 4 + i;
        if (gr < nrows) Y[gr * 64 + c] = dinv[gr] * acc[i];
    }
}

// ---------------- gather + self-loop + bias + relu ----------------
// one wave per node; 16 lanes x float4; 4 edge-slots x 2-deep = 8 rows in flight
__global__ __launch_bounds__(256) void k_gather(const float* __restrict__ xwp,
                                                const float* __restrict__ dinv,
                                                const int* __restrict__ row_ptr,
                                                const int* __restrict__ csr_src,
                                                const float* __restrict__ bias,
                                                float* __restrict__ hout) {
    int wave = threadIdx.x >> 6;
    int lane = threadIdx.x & 63;
    int n = blockIdx.x * 4 + wave;
    if (n >= N_NODES) return;
    int sub = lane >> 4, c4 = lane & 15;
    int start = row_ptr[n], end = row_ptr[n + 1];
    float ax = 0.f, ay = 0.f, az = 0.f, aw = 0.f;
    int i = start + sub;
    for (; i + 4 < end; i += 8) {
        int s0 = csr_src[i];
        int s1 = csr_src[i + 4];
        const float4 v0 = *(const float4*)(xwp + (size_t)s0 * 64 + c4 * 4);
        const float4 v1 = *(const float4*)(xwp + (size_t)s1 * 64 + c4 * 4);
        ax += v0.x + v1.x; ay += v0.y + v1.y;
        az += v0.z + v1.z; aw += v0.w + v1.w;
    }
    if (i < end) {
        int s = csr_src[i];
        const float4 v = *(const float4*)(xwp + (size_t)s * 64 + c4 * 4);
        ax += v.x; ay += v.y; az += v.z; aw += v.w;
    }
    // reduce over the 4 edge-slots (lane^16, lane^32)
    ax += __shfl_xor(ax, 16, 64); ay += __shfl_xor(ay, 16, 64);
    az += __shfl_xor(az, 16, 64); aw += __shfl_xor(aw, 16, 64);
    ax += __shfl_xor(ax, 32, 64); ay += __shfl_xor(ay, 32, 64);
    az += __shfl_xor(az, 32, 64); aw += __shfl_xor(aw, 32, 64);
    if (sub == 0) {
        float dn = dinv[n];
        const float4 xn = *(const float4*)(xwp + (size_t)n * 64 + c4 * 4);
        const float4 bv = *(const float4*)(bias + c4 * 4);
        float4 r;
        r.x = fmaxf(dn * (ax + xn.x) + bv.x, 0.f);
        r.y = fmaxf(dn * (ay + xn.y) + bv.y, 0.f);
        r.z = fmaxf(dn * (az + xn.z) + bv.z, 0.f);
        r.w = fmaxf(dn * (aw + xn.w) + bv.w, 0.f);
        *(float4*)(hout + (size_t)n * 64 + c4 * 4) = r;
    }
}

// ---------------- mean pool (batch is sorted) ----------------
__device__ __forceinline__ int lower_bound(const int* __restrict__ a, int n, int key) {
    int lo = 0, hi = n;
    while (lo < hi) {
        int mid = (lo + hi) >> 1;
        if (a[mid] < key) lo = mid + 1; else hi = mid;
    }
    return lo;
}

__global__ void k_pool(const float* __restrict__ h, const int* __restrict__ batch,
                       float* __restrict__ g) {
    int b = blockIdx.x;
    int t = threadIdx.x, c = t & 63, rg = t >> 6;
    __shared__ float s[4][64];
    int start = lower_bound(batch, N_NODES, b);
    int end   = lower_bound(batch, N_NODES, b + 1);
    float sum = 0.f;
    for (int n = start + rg; n < end; n += 4) sum += h[(size_t)n * 64 + c];
    s[rg][c] = sum;
    __syncthreads();
    if (rg == 0) {
        float tot = s[0][c] + s[1][c] + s[2][c] + s[3][c];
        float cntf = (float)(end - start);
        g[b * 64 + c] = tot / fmaxf(cntf, 1.0f);
    }
}

// ---------------- final linear  out[128,128] = g[128,64] @ Wl[64,128] + bl --
__global__ void k_final(const float* __restrict__ g, const float* __restrict__ Wl,
                        const float* __restrict__ bl, float* __restrict__ out) {
    __shared__ float gs[64];
    int row = blockIdx.x, c = threadIdx.x;
    if (c < 64) gs[c] = g[row * 64 + c];
    __syncthreads();
    float acc = bl[c];
#pragma unroll
    for (int k = 0; k < 64; ++k) acc += gs[k] * Wl[k * 128 + c];
    out[row * 128 + c] = acc;
}

extern "C" void kernel_launch(void* const* d_in, const int* in_sizes, int n_in,
                              void* d_out, int out_size, void* d_ws, size_t ws_size,
                              hipStream_t stream) {
    const float* x    = (const float*)d_in[0];
    const int*   ei   = (const int*)d_in[1];
    const int*   batch= (const int*)d_in[2];
    const float* W1   = (const float*)d_in[3];
    const float* b1   = (const float*)d_in[4];
    const float* W2   = (const float*)d_in[5];
    const float* b2   = (const float*)d_in[6];
    const float* Wl   = (const float*)d_in[7];
    const float* bl   = (const float*)d_in[8];
    float* out = (float*)d_out;

    const int* src = ei;
    const int* dst = ei + N_EDGES;

    // workspace layout (offsets 256B aligned)
    char* base = (char*)d_ws;
    int*          cnt      = (int*)  (base + 0);           // 400 KB
    float*        dinv     = (float*)(base + 400128);      // 400 KB
    int*          row_ptr  = (int*)  (base + 800256);      // 400 KB (N+1 ints)
    int*          bkt_cur  = (int*)  (base + 1200384);     // NBKT*4
    int*          bsums    = (int*)  (base + 1202432);     // 2 KB
    int*          csr_src  = (int*)  (base + 1204480);     // 12.8 MB
    float*        bufA     = (float*)(base + 14004480);    // 25.6 MB
    float*        bufB     = (float*)(base + 39604480);    // 25.6 MB
    float*        g        = (float*)(base + 65204480);    // 32 KB
    // recs aliases bufA: consumed by k_csr before k_gemm writes bufA
    unsigned int* recs     = (unsigned int*)bufA;

    const int NB_SCAN = (N_NODES + 255) / 256;     // 391
    const int GB_E    = (N_EDGES + 255) / 256;     // 12500
    const int GB_N    = (N_NODES + 255) / 256;     // 391

    hipMemsetAsync(cnt, 0, N_NODES * sizeof(int), stream);
    k_count<<<GB_E, 256, 0, stream>>>(dst, cnt);
    k_dinv <<<GB_N, 256, 0, stream>>>(cnt, dinv);
    k_scan1<<<NB_SCAN, 256, 0, stream>>>(cnt, row_ptr, bsums);
    k_scan2<<<1, 512, 0, stream>>>(bsums, NB_SCAN);
    k_scan3<<<NB_SCAN, 256, 0, stream>>>(row_ptr, bsums, bkt_cur);
    k_bin  <<<BIN_BLOCKS, 256, 0, stream>>>(src, dst, bkt_cur, recs);
    k_csr  <<<NBKT, 256, 0, stream>>>(recs, row_ptr, csr_src);

    // layer 1: bufA = dinv .* (x @ W1); bufB = relu(dinv.*(agg + bufA) + b1)
    k_gemm<IN_DIM><<<(N_NODES + 15) / 16, 256, 0, stream>>>(x, W1, dinv, bufA, N_NODES);
    k_gather<<<(N_NODES + 3) / 4, 256, 0, stream>>>(bufA, dinv, row_ptr, csr_src, b1, bufB);

    // layer 2
    k_gemm<HID><<<(N_NODES + 15) / 16, 256, 0, stream>>>(bufB, W2, dinv, bufA, N_NODES);
    k_gather<<<(N_NODES + 3) / 4, 256, 0, stream>>>(bufA, dinv, row_ptr, csr_src, b2, bufB);

    // pool + final linear
    k_pool <<<N_GRAPHS, 256, 0, stream>>>(bufB, batch, g);
    k_final<<<N_GRAPHS, 128, 0, stream>>>(g, Wl, bl, out);
}

// Round 4
// 341.588 us; speedup vs baseline: 8.9186x; 1.6548x over previous
//
#include <hip/hip_runtime.h>
#include <math.h>

#define N_NODES    100000
#define N_EDGES    3200000
#define N_GRAPHS   128
#define IN_DIM     128
#define HID        64
#define OUT_DIM    128
#define NBKT       391          // ceil(N_NODES / 256)
#define BIN_BLOCKS 512
#define E_PER_BIN  6250         // N_EDGES / BIN_BLOCKS (exact)

typedef unsigned short ushort_t;

__device__ __forceinline__ float bf2f(ushort_t u) {
    return __uint_as_float(((unsigned int)u) << 16);
}
__device__ __forceinline__ ushort_t f2bf(float f) {
    unsigned int u = __float_as_uint(f);
    u += 0x7FFFu + ((u >> 16) & 1u);        // round to nearest even
    return (ushort_t)(u >> 16);
}

// ---------------- per-bucket edge histogram (bucket = dst >> 8) -------------
__global__ __launch_bounds__(256) void k_bkt_hist(const int* __restrict__ dst,
                                                  int* __restrict__ bkt_cnt) {
    __shared__ int hist[NBKT];
    int t = threadIdx.x;
    for (int b = t; b < NBKT; b += 256) hist[b] = 0;
    __syncthreads();
    int e0 = blockIdx.x * E_PER_BIN;
    for (int e = e0 + t; e < e0 + E_PER_BIN; e += 256)
        atomicAdd(&hist[dst[e] >> 8], 1);
    __syncthreads();
    for (int b = t; b < NBKT; b += 256) {
        int h = hist[b];
        if (h) atomicAdd(&bkt_cnt[b], h);
    }
}

// ---------------- exclusive scan over bucket counts (single block) ----------
__global__ void k_scan_bkt(const int* __restrict__ bkt_cnt,
                           int* __restrict__ bkt_ptr, int* __restrict__ bkt_cur) {
    __shared__ int s[512];
    int t = threadIdx.x;
    int v = (t < NBKT) ? bkt_cnt[t] : 0;
    s[t] = v; __syncthreads();
    for (int d = 1; d < 512; d <<= 1) {
        int add = (t >= d) ? s[t - d] : 0;
        __syncthreads();
        s[t] += add;
        __syncthreads();
    }
    int excl = s[t] - v;
    if (t <= NBKT) bkt_ptr[t] = excl;       // bkt_ptr[NBKT] = N_EDGES
    if (t < NBKT)  bkt_cur[t] = excl;
}

// ---------------- multisplit binning: recs[pos] = (src<<8)|dst_local --------
__global__ __launch_bounds__(256) void k_bin(const int* __restrict__ src,
                                             const int* __restrict__ dst,
                                             int* __restrict__ bkt_cursor,
                                             unsigned int* __restrict__ recs) {
    __shared__ int hist[NBKT];
    __shared__ int base[NBKT];
    int t = threadIdx.x;
    int e0 = blockIdx.x * E_PER_BIN;
    int e1 = e0 + E_PER_BIN;                 // exact: 512*6250 = 3.2M
    for (int b = t; b < NBKT; b += 256) hist[b] = 0;
    __syncthreads();
    for (int e = e0 + t; e < e1; e += 256)
        atomicAdd(&hist[dst[e] >> 8], 1);
    __syncthreads();
    for (int b = t; b < NBKT; b += 256) {
        int h = hist[b];
        base[b] = h ? atomicAdd(&bkt_cursor[b], h) : 0;
        hist[b] = 0;
    }
    __syncthreads();
    for (int e = e0 + t; e < e1; e += 256) {
        int d = dst[e];
        int b = d >> 8;
        int pos = base[b] + atomicAdd(&hist[b], 1);
        recs[pos] = ((unsigned int)src[e] << 8) | (unsigned int)(d & 255);
    }
}

// ---------------- per-bucket: counts -> row_ptr + dinv + CSR placement ------
__global__ __launch_bounds__(256) void k_csrA(const unsigned int* __restrict__ recs,
                                              const int* __restrict__ bkt_ptr,
                                              int* __restrict__ row_ptr,
                                              float* __restrict__ dinv,
                                              int* __restrict__ csr_src) {
    __shared__ int lcnt[256];
    __shared__ int s[256];
    __shared__ int lcur[256];
    int b = blockIdx.x, t = threadIdx.x;
    int start = bkt_ptr[b], end = bkt_ptr[b + 1];
    lcnt[t] = 0;
    __syncthreads();
    for (int i = start + t; i < end; i += 256)
        atomicAdd(&lcnt[recs[i] & 255u], 1);
    __syncthreads();
    int v = lcnt[t];
    s[t] = v; __syncthreads();
    for (int d = 1; d < 256; d <<= 1) {
        int add = (t >= d) ? s[t - d] : 0;
        __syncthreads();
        s[t] += add;
        __syncthreads();
    }
    int excl = s[t] - v;
    int n = b * 256 + t;
    if (n <= N_NODES) row_ptr[n] = start + excl;   // n==N_NODES -> N_EDGES
    if (n < N_NODES)  dinv[n] = 1.0f / sqrtf((float)v + 1.0f);
    lcur[t] = start + excl;
    __syncthreads();
    for (int i = start + t; i < end; i += 256) {
        unsigned int r = recs[i];
        int p = atomicAdd(&lcur[r & 255u], 1);
        csr_src[p] = (int)(r >> 8);
    }
}

// ------- dense GEMM  Ybf[N,64] = bf16( dinv[n] * (X[N,K] @ W[K,64]) ) -------
template <int K>
__global__ __launch_bounds__(256) void k_gemm(const float* __restrict__ X,
                                              const float* __restrict__ W,
                                              const float* __restrict__ dinv,
                                              ushort_t* __restrict__ Ybf, int nrows) {
    __shared__ float Ws[K * 64];
    __shared__ float Xs[16][K];
    int t = threadIdx.x;
    for (int i = t; i < K * 64; i += 256) Ws[i] = W[i];
    int row0 = blockIdx.x * 16;
    for (int i = t; i < 16 * K; i += 256) {
        int r = i / K, k = i % K;
        int gr = row0 + r;
        Xs[r][k] = (gr < nrows) ? X[gr * K + k] : 0.0f;
    }
    __syncthreads();
    int c = t & 63, rg = t >> 6;
    float acc[4] = {0.f, 0.f, 0.f, 0.f};
#pragma unroll 4
    for (int k = 0; k < K; ++k) {
        float w = Ws[k * 64 + c];
#pragma unroll
        for (int i = 0; i < 4; ++i) acc[i] += Xs[rg * 4 + i][k] * w;
    }
#pragma unroll
    for (int i = 0; i < 4; ++i) {
        int gr = row0 + rg * 4 + i;
        if (gr < nrows) Ybf[(size_t)gr * 64 + c] = f2bf(dinv[gr] * acc[i]);
    }
}

// ---------------- gather (bf16 table) + self-loop + bias + relu -------------
// one wave per node; 16 lanes x 4 bf16; 4 edge-slots x 2-deep = 8 rows in flight
__global__ __launch_bounds__(256) void k_gather(const ushort_t* __restrict__ xwp,
                                                const float* __restrict__ dinv,
                                                const int* __restrict__ row_ptr,
                                                const int* __restrict__ csr_src,
                                                const float* __restrict__ bias,
                                                float* __restrict__ hout) {
    int wave = threadIdx.x >> 6;
    int lane = threadIdx.x & 63;
    int n = blockIdx.x * 4 + wave;
    if (n >= N_NODES) return;
    int sub = lane >> 4, c4 = lane & 15;
    int start = row_ptr[n], end = row_ptr[n + 1];
    float ax = 0.f, ay = 0.f, az = 0.f, aw = 0.f;
    int i = start + sub;
    for (; i + 4 < end; i += 8) {
        int s0 = csr_src[i];
        int s1 = csr_src[i + 4];
        const ushort4 v0 = *(const ushort4*)(xwp + (size_t)s0 * 64 + c4 * 4);
        const ushort4 v1 = *(const ushort4*)(xwp + (size_t)s1 * 64 + c4 * 4);
        ax += bf2f(v0.x) + bf2f(v1.x); ay += bf2f(v0.y) + bf2f(v1.y);
        az += bf2f(v0.z) + bf2f(v1.z); aw += bf2f(v0.w) + bf2f(v1.w);
    }
    if (i < end) {
        int s0 = csr_src[i];
        const ushort4 v = *(const ushort4*)(xwp + (size_t)s0 * 64 + c4 * 4);
        ax += bf2f(v.x); ay += bf2f(v.y); az += bf2f(v.z); aw += bf2f(v.w);
    }
    ax += __shfl_xor(ax, 16, 64); ay += __shfl_xor(ay, 16, 64);
    az += __shfl_xor(az, 16, 64); aw += __shfl_xor(aw, 16, 64);
    ax += __shfl_xor(ax, 32, 64); ay += __shfl_xor(ay, 32, 64);
    az += __shfl_xor(az, 32, 64); aw += __shfl_xor(aw, 32, 64);
    if (sub == 0) {
        float dn = dinv[n];
        const ushort4 xn = *(const ushort4*)(xwp + (size_t)n * 64 + c4 * 4);
        const float4 bv = *(const float4*)(bias + c4 * 4);
        float4 r;
        r.x = fmaxf(dn * (ax + bf2f(xn.x)) + bv.x, 0.f);
        r.y = fmaxf(dn * (ay + bf2f(xn.y)) + bv.y, 0.f);
        r.z = fmaxf(dn * (az + bf2f(xn.z)) + bv.z, 0.f);
        r.w = fmaxf(dn * (aw + bf2f(xn.w)) + bv.w, 0.f);
        *(float4*)(hout + (size_t)n * 64 + c4 * 4) = r;
    }
}

// ---------------- mean pool (batch is sorted) ----------------
__device__ __forceinline__ int lower_bound(const int* __restrict__ a, int n, int key) {
    int lo = 0, hi = n;
    while (lo < hi) {
        int mid = (lo + hi) >> 1;
        if (a[mid] < key) lo = mid + 1; else hi = mid;
    }
    return lo;
}

__global__ __launch_bounds__(1024) void k_pool(const float* __restrict__ h,
                                               const int* __restrict__ batch,
                                               float* __restrict__ g) {
    int b = blockIdx.x;
    int t = threadIdx.x, c = t & 63, rg = t >> 6;   // 16 row-groups
    __shared__ float s[16][64];
    int start = lower_bound(batch, N_NODES, b);
    int end   = lower_bound(batch, N_NODES, b + 1);
    float sum = 0.f;
    for (int n = start + rg; n < end; n += 16) sum += h[(size_t)n * 64 + c];
    s[rg][c] = sum;
    __syncthreads();
    if (rg == 0) {
        float tot = 0.f;
#pragma unroll
        for (int k = 0; k < 16; ++k) tot += s[k][c];
        float cntf = (float)(end - start);
        g[b * 64 + c] = tot / fmaxf(cntf, 1.0f);
    }
}

// ---------------- final linear  out[128,128] = g[128,64] @ Wl[64,128] + bl --
__global__ void k_final(const float* __restrict__ g, const float* __restrict__ Wl,
                        const float* __restrict__ bl, float* __restrict__ out) {
    __shared__ float gs[64];
    int row = blockIdx.x, c = threadIdx.x;
    if (c < 64) gs[c] = g[row * 64 + c];
    __syncthreads();
    float acc = bl[c];
#pragma unroll
    for (int k = 0; k < 64; ++k) acc += gs[k] * Wl[k * 128 + c];
    out[row * 128 + c] = acc;
}

extern "C" void kernel_launch(void* const* d_in, const int* in_sizes, int n_in,
                              void* d_out, int out_size, void* d_ws, size_t ws_size,
                              hipStream_t stream) {
    const float* x    = (const float*)d_in[0];
    const int*   ei   = (const int*)d_in[1];
    const int*   batch= (const int*)d_in[2];
    const float* W1   = (const float*)d_in[3];
    const float* b1   = (const float*)d_in[4];
    const float* W2   = (const float*)d_in[5];
    const float* b2   = (const float*)d_in[6];
    const float* Wl   = (const float*)d_in[7];
    const float* bl   = (const float*)d_in[8];
    float* out = (float*)d_out;

    const int* src = ei;
    const int* dst = ei + N_EDGES;

    // workspace layout (offsets 128B aligned)
    char* base = (char*)d_ws;
    float*        dinv     = (float*)(base + 0);           // 400 KB
    int*          row_ptr  = (int*)  (base + 400128);      // 400 KB (N+1)
    int*          bkt_cnt  = (int*)  (base + 800256);      // 2 KB
    int*          bkt_ptr  = (int*)  (base + 802304);      // 2 KB
    int*          bkt_cur  = (int*)  (base + 804352);      // 2 KB
    int*          csr_src  = (int*)  (base + 806400);      // 12.8 MB
    ushort_t*     xwp      = (ushort_t*)(base + 13606400); // 12.8 MB (bf16 table)
    float*        h        = (float*)(base + 26406400);    // 25.6 MB
    float*        g        = (float*)(base + 52006400);    // 32 KB
    // recs aliases xwp: consumed by k_csrA before k_gemm writes xwp
    unsigned int* recs     = (unsigned int*)xwp;

    hipMemsetAsync(bkt_cnt, 0, NBKT * sizeof(int), stream);
    k_bkt_hist<<<BIN_BLOCKS, 256, 0, stream>>>(dst, bkt_cnt);
    k_scan_bkt<<<1, 512, 0, stream>>>(bkt_cnt, bkt_ptr, bkt_cur);
    k_bin     <<<BIN_BLOCKS, 256, 0, stream>>>(src, dst, bkt_cur, recs);
    k_csrA    <<<NBKT, 256, 0, stream>>>(recs, bkt_ptr, row_ptr, dinv, csr_src);

    // layer 1: xwp = bf16(dinv .* (x @ W1)); h = relu(dinv.*(agg + xwp) + b1)
    k_gemm<IN_DIM><<<(N_NODES + 15) / 16, 256, 0, stream>>>(x, W1, dinv, xwp, N_NODES);
    k_gather<<<(N_NODES + 3) / 4, 256, 0, stream>>>(xwp, dinv, row_ptr, csr_src, b1, h);

    // layer 2 (xwp reused; h overwritten in place by gather2)
    k_gemm<HID><<<(N_NODES + 15) / 16, 256, 0, stream>>>(h, W2, dinv, xwp, N_NODES);
    k_gather<<<(N_NODES + 3) / 4, 256, 0, stream>>>(xwp, dinv, row_ptr, csr_src, b2, h);

    // pool + final linear
    k_pool <<<N_GRAPHS, 1024, 0, stream>>>(h, batch, g);
    k_final<<<N_GRAPHS, 128, 0, stream>>>(g, Wl, bl, out);
}